// Round 13
// baseline (680.982 us; speedup 1.0000x reference)
//
#include <hip/hip_runtime.h>
#include <stdint.h>

#define TT_ 4096
#define CC_ 192
#define TILE_ 64
#define HALO_ 13
#define TW_ 90
#define YTS_ 200    // row stride (shorts) for BOTH H and YT = 100 dwords
#define NT_ 512

typedef float f32x2 __attribute__((ext_vector_type(2)));
typedef float f32x4 __attribute__((ext_vector_type(4)));
typedef short s16x8 __attribute__((ext_vector_type(8)));
typedef uint32_t ui32x2 __attribute__((ext_vector_type(2)));
typedef uint32_t ui32x4 __attribute__((ext_vector_type(4)));

__device__ __forceinline__ float bf2f(short s){
  uint32_t u = ((uint32_t)(uint16_t)s) << 16;
  float f; __builtin_memcpy(&f, &u, 4); return f;
}
// extract bf16 half of a dword as f32: hi=0 -> low short, hi=1 -> high short
__device__ __forceinline__ float bfhalf(uint32_t u, int hi){
  uint32_t v = hi ? (u & 0xFFFF0000u) : (u << 16);
  float f; __builtin_memcpy(&f, &v, 4); return f;
}
__device__ __forceinline__ short f2bf(float f){
  uint32_t u; __builtin_memcpy(&u, &f, 4);
  u += 0x7FFFu + ((u >> 16) & 1u);   // RNE
  return (short)(u >> 16);
}
__device__ __forceinline__ uint32_t fbits(float f){
  uint32_t u; __builtin_memcpy(&u, &f, 4); return u;
}
// pack two f32 -> two bf16 (TRUNCATE) in ONE v_perm_b32. low16 = lo, high16 = hi.
__device__ __forceinline__ uint32_t pk_trunc(float lo, float hi){
  return __builtin_amdgcn_perm(fbits(hi), fbits(lo), 0x07060302u);
}
__device__ __forceinline__ uint32_t rne_u(float f){
  uint32_t u = fbits(f);
  return u + 0x7FFFu + ((u >> 16) & 1u);
}
// pack two f32 -> two bf16 (RNE): 2x3 ops + 1 perm
__device__ __forceinline__ uint32_t pk_rne(float lo, float hi){
  return __builtin_amdgcn_perm(rne_u(hi), rne_u(lo), 0x07060302u);
}
// tanh-form GELU, log2e folded (r10-proven constants), scalar
__device__ __forceinline__ float gelu_f(float x){
  float t = x*x;
  float p = x*__builtin_fmaf(t, 0.1029432609f, 2.3022085351f);
  float e = __builtin_amdgcn_exp2f(-p);
  return x * __builtin_amdgcn_rcpf(1.0f + e);
}
// packed GELU on 2 elements: muls/fmas pack to v_pk_*; exp2/rcp stay scalar (trans pipe)
__device__ __forceinline__ f32x2 gelu_pk(f32x2 x){
  f32x2 t = x*x;
  f32x2 p = x * __builtin_elementwise_fma(t, f32x2{0.1029432609f,0.1029432609f},
                                             f32x2{2.3022085351f,2.3022085351f});
  f32x2 r;
  r[0] = __builtin_amdgcn_rcpf(1.0f + __builtin_amdgcn_exp2f(-p[0]));
  r[1] = __builtin_amdgcn_rcpf(1.0f + __builtin_amdgcn_exp2f(-p[1]));
  return x*r;
}
// granule swizzle (shared by H and YT): 16B granule g of row r stored at g ^ (r&3).
// Spreads strided row accesses to the bank floor; granule parity must be mixed
// across the wave (see ln_stats).
__device__ __forceinline__ int ytix(int row, int col){
  return row*YTS_ + ((((col >> 3) ^ (row & 3)) << 3) | (col & 7));
}

// ---- depthwise conv, time-major, FIXED-GRANULE (r5-proven), SCALAR math
template<int D>
__device__ __forceinline__ void dw_pass(const short* __restrict__ Hs, short* __restrict__ YTs,
    const float* __restrict__ sw, const float* __restrict__ sb,
    int jlo, int jhi, int tid){
  if (tid >= 504) return;
  const int gr = tid % 24, r0 = tid / 24;
  const int c0 = gr*8;
  float wv[24], bw[8];
  #pragma unroll
  for (int u=0;u<6;++u) *(f32x4*)&wv[u*4] = *(const f32x4*)&sw[c0*3 + u*4];
  *(f32x4*)&bw[0] = *(const f32x4*)&sb[c0];
  *(f32x4*)&bw[4] = *(const f32x4*)&sb[c0+4];
  for (int j = jlo + r0; j < jhi; j += 21){
    s16x8 t0 = *(const s16x8*)(Hs + ytix(j-D, c0));
    s16x8 t1 = *(const s16x8*)(Hs + ytix(j,   c0));
    s16x8 t2 = *(const s16x8*)(Hs + ytix(j+D, c0));
    float v[8];
    #pragma unroll
    for (int e=0;e<8;++e){
      v[e] = __builtin_fmaf(wv[e*3+0], bf2f(t0[e]),
             __builtin_fmaf(wv[e*3+1], bf2f(t1[e]),
             __builtin_fmaf(wv[e*3+2], bf2f(t2[e]), bw[e])));
    }
    ui32x4 o;
    #pragma unroll
    for (int e=0;e<4;++e) o[e] = pk_trunc(v[2*e], v[2*e+1]);   // trunc: LN follows
    *(ui32x4*)(YTs + ytix(j, c0)) = o;
  }
}

// ---- per-time-row LN stats; 4 threads/row, quad shuffle; packed f32x2 accumulate.
// Column slice: granules {qtr+4u} (col = qtr*8 + u*32) -> wave granule parity
// follows qtr (32/32 even-odd) -> bank floor (r10-proven, -9% conflicts).
__device__ __forceinline__ void ln_stats(const short* __restrict__ YTs, float* __restrict__ SM,
                                         float* __restrict__ SR, int jlo, int jhi, int tid){
  if (tid < 384){
    int row = tid >> 2, qtr = tid & 3;
    if (row >= jlo && row < jhi){
      f32x2 sp = {0.f,0.f}, qp = {0.f,0.f};
      #pragma unroll
      for (int u=0;u<6;++u){
        ui32x4 v = *(const ui32x4*)(YTs + ytix(row, qtr*8 + u*32));
        #pragma unroll
        for (int d=0;d<4;++d){
          f32x2 f = f32x2{bfhalf(v[d],0), bfhalf(v[d],1)};
          sp += f; qp = __builtin_elementwise_fma(f, f, qp);
        }
      }
      float s = sp[0]+sp[1], q = qp[0]+qp[1];
      s += __shfl_xor(s,1); q += __shfl_xor(q,1);
      s += __shfl_xor(s,2); q += __shfl_xor(q,2);
      if (qtr==0){
        float mean = s*(1.f/192.f);
        float var = fmaxf(q*(1.f/192.f) - mean*mean, 0.f);
        SM[row]=mean; SR[row]=rsqrtf(var+1e-5f);
      }
    }
  }
}

__global__ __launch_bounds__(512, 4)
void convflow_main(
    const float* __restrict__ x, const float* __restrict__ xmask,
    const float* __restrict__ pre_w, const float* __restrict__ pre_b,
    const float* __restrict__ sep_w, const float* __restrict__ sep_b,
    const float* __restrict__ pw_b,
    const float* __restrict__ ln1_g, const float* __restrict__ ln1_b,
    const float* __restrict__ ln2_g, const float* __restrict__ ln2_b,
    const float* __restrict__ proj_b,
    const short* __restrict__ Wbf, const short* __restrict__ Pbf,
    float* __restrict__ out, float* __restrict__ part)
{
  __shared__ __align__(16) char smem_raw[78592];
  float* MB = (float*)(smem_raw + 0);        // [160]: mask at idx j+16, zero outside valid t
  float* XB = (float*)(smem_raw + 640);      // [96]
  float* SM = (float*)(smem_raw + 1024);     // [96]
  float* SR = (float*)(smem_raw + 1408);     // [96]
  short* H  = (short*)(smem_raw + 1792);     // [96][200] bf16 time-major, granule-swizzled
  short* YT = (short*)(smem_raw + 40192);    // [96][200] bf16 time-major, granule-swizzled
  float* HP = (float*)(smem_raw + 65792);    // alias YT rows 64..95: [64][33] proj out

  const int tid = threadIdx.x;
  const int b = blockIdx.y, tile = blockIdx.x;
  const int t0 = tile*TILE_ - HALO_;

  // ---- setup mask + x0 window
  for (int idx = tid; idx < 160; idx += NT_){
    int j = idx - 16; int t = t0 + j;
    float m = 0.f;
    if (j >= 0 && j < TW_ && t >= 0 && t < TT_) m = xmask[b*TT_ + t];
    MB[idx] = m;
  }
  if (tid < 96){
    int t = t0 + tid; float v = 0.f;
    if (tid < TW_ && t >= 0 && t < TT_) v = x[(b*2)*TT_ + t];
    XB[tid] = v;
  }
  __syncthreads();

  // ---- h0 = (pre_w*x0 + pre_b)*mask -> H bf16 (RNE); fixed-granule, PACKED
  if (tid < 504){
    const int gr = tid % 24, r0 = tid / 24;
    const int c = gr*8;
    f32x2 wp[4], bp[4];
    #pragma unroll
    for (int p=0;p<4;++p){
      wp[p] = f32x2{pre_w[c+2*p], pre_w[c+2*p+1]};
      bp[p] = f32x2{pre_b[c+2*p], pre_b[c+2*p+1]};
    }
    for (int j = r0; j < 96; j += 21){
      float xv = XB[j], mv = MB[16+j];
      ui32x4 o;
      #pragma unroll
      for (int p=0;p<4;++p){
        f32x2 t = __builtin_elementwise_fma(wp[p], f32x2{xv,xv}, bp[p]) * f32x2{mv,mv};
        o[p] = pk_rne(t[0], t[1]);
      }
      *(ui32x4*)(H + ytix(j, c)) = o;
    }
  }
  __syncthreads();

  // ---- 3 WN layers
  #pragma unroll 1
  for (int li = 0; li < 3; ++li){
    const int jlo = (li==0) ? 1 : ((li==1) ? 4 : 13);
    const int jhi = (li==0) ? 89 : ((li==1) ? 86 : 77);
    const float* sw = sep_w + li*CC_*3;
    const float* sb = sep_b + li*CC_;

    if (li == 0)      dw_pass<1>(H, YT, sw, sb, jlo, jhi, tid);
    else if (li == 1) dw_pass<3>(H, YT, sw, sb, jlo, jhi, tid);
    else              dw_pass<9>(H, YT, sw, sb, jlo, jhi, tid);
    __syncthreads();

    ln_stats(YT, SM, SR, jlo, jhi, tid); __syncthreads();

    // ---- LN1 + gelu in place on YT; valid rows only; PACKED
    {
      const float* g1 = ln1_g + li*CC_;
      const float* b1 = ln1_b + li*CC_;
      if (tid < 504){
        const int gr = tid % 24, r0 = tid / 24;
        const int c0 = gr*8;
        f32x2 gp[4], bp[4];
        #pragma unroll
        for (int p=0;p<4;++p){
          gp[p] = f32x2{g1[c0+2*p], g1[c0+2*p+1]};
          bp[p] = f32x2{b1[c0+2*p], b1[c0+2*p+1]};
        }
        for (int row = jlo + r0; row < jhi; row += 21){
          const float m = SM[row], r = SR[row];
          short* pptr = YT + ytix(row, c0);
          ui32x4 v = *(const ui32x4*)pptr;
          ui32x4 o;
          #pragma unroll
          for (int p=0;p<4;++p){
            f32x2 rg = gp[p] * f32x2{r,r};
            f32x2 cp = __builtin_elementwise_fma(f32x2{-m,-m}, rg, bp[p]);
            f32x2 xp = f32x2{bfhalf(v[p],0), bfhalf(v[p],1)};
            f32x2 ov = gelu_pk(__builtin_elementwise_fma(xp, rg, cp));
            o[p] = pk_trunc(ov[0], ov[1]);
          }
          *(ui32x4*)pptr = o;
        }
      }
    }
    __syncthreads();

    // ---- pointwise 192x192 GEMM in place on YT, N-SPLIT into two phases:
    // peak accumulator footprint 36 -> 24 AGPRs. Theory (r8/r11/r12 spill chain):
    // unified file budget = 128/wave split arch-64 + agpr-64; attributes can't
    // move the split, shrinking the accumulator can -> frees arch headroom for
    // the packed LN bodies. Hazard-free: phase-A writes rows {0-31,48-79},
    // phase-B reads rows {32-47,80-95} (disjoint).
    {
      int w = tid >> 6, lane = tid & 63, l16 = lane & 15, q = lane >> 4;
      int Mh = w & 3, Nh = w >> 2;
      const short* Wl = Wbf + li*CC_*CC_;
      // phase A: N-tiles s=0,1  (acc 3x2 = 24)
      {
        f32x4 acc[3][2];
        #pragma unroll
        for (int r=0;r<3;r++)
          #pragma unroll
          for (int s=0;s<2;s++){ f32x4 z = {0.f,0.f,0.f,0.f}; acc[r][s] = z; }
        #pragma unroll
        for (int kk=0;kk<6;++kk){
          s16x8 bv[2], av[3];
          #pragma unroll
          for (int s=0;s<2;++s)
            bv[s] = *(const s16x8*)&YT[ytix((Nh*3+s)*16 + l16, kk*32 + q*8)];
          #pragma unroll
          for (int r=0;r<3;++r)
            av[r] = *(const s16x8*)&Wl[((Mh*3+r)*16 + l16)*CC_ + kk*32 + q*8];
          #pragma unroll
          for (int r=0;r<3;++r)
            #pragma unroll
            for (int s=0;s<2;++s)
              acc[r][s] = __builtin_amdgcn_mfma_f32_16x16x32_bf16(av[r], bv[s], acc[r][s], 0, 0, 0);
        }
        __syncthreads();   // all phase-A B-reads complete before s01-row writes
        #pragma unroll
        for (int r=0;r<3;++r){
          int m0 = (Mh*3+r)*16 + q*4;
          f32x4 bias = *(const f32x4*)&pw_b[li*CC_ + m0];
          #pragma unroll
          for (int s=0;s<2;++s){
            int n = (Nh*3+s)*16 + l16;
            ui32x2 ov;
            ov[0] = pk_trunc(acc[r][s][0]+bias[0], acc[r][s][1]+bias[1]);
            ov[1] = pk_trunc(acc[r][s][2]+bias[2], acc[r][s][3]+bias[3]);
            *(ui32x2*)(YT + ytix(n, m0)) = ov;
          }
        }
      }
      // phase B: N-tile s=2  (acc 3x1 = 12; reads disjoint from phase-A writes)
      {
        f32x4 accB[3];
        #pragma unroll
        for (int r=0;r<3;r++){ f32x4 z = {0.f,0.f,0.f,0.f}; accB[r] = z; }
        #pragma unroll
        for (int kk=0;kk<6;++kk){
          s16x8 av[3];
          s16x8 bvv = *(const s16x8*)&YT[ytix((Nh*3+2)*16 + l16, kk*32 + q*8)];
          #pragma unroll
          for (int r=0;r<3;++r)
            av[r] = *(const s16x8*)&Wl[((Mh*3+r)*16 + l16)*CC_ + kk*32 + q*8];
          #pragma unroll
          for (int r=0;r<3;++r)
            accB[r] = __builtin_amdgcn_mfma_f32_16x16x32_bf16(av[r], bvv, accB[r], 0, 0, 0);
        }
        __syncthreads();   // all phase-B reads complete before s2-row writes
        #pragma unroll
        for (int r=0;r<3;++r){
          int m0 = (Mh*3+r)*16 + q*4;
          f32x4 bias = *(const f32x4*)&pw_b[li*CC_ + m0];
          int n = (Nh*3+2)*16 + l16;
          ui32x2 ov;
          ov[0] = pk_trunc(accB[r][0]+bias[0], accB[r][1]+bias[1]);
          ov[1] = pk_trunc(accB[r][2]+bias[2], accB[r][3]+bias[3]);
          *(ui32x2*)(YT + ytix(n, m0)) = ov;
        }
        __syncthreads();
      }
    }

    ln_stats(YT, SM, SR, jlo, jhi, tid); __syncthreads();

    // ---- LN2 + gelu + residual into H; fixed-granule; PACKED
    {
      const float* g2 = ln2_g + li*CC_;
      const float* b2 = ln2_b + li*CC_;
      if (tid < 504){
        const int gr = tid % 24, r0 = tid / 24;
        const int c0 = gr*8;
        f32x2 gp[4], bp[4];
        #pragma unroll
        for (int p=0;p<4;++p){
          gp[p] = f32x2{g2[c0+2*p], g2[c0+2*p+1]};
          bp[p] = f32x2{b2[c0+2*p], b2[c0+2*p+1]};
        }
        for (int row = jlo + r0; row < jhi; row += 21){
          const float m = SM[row], r = SR[row], mk = MB[16+row];
          ui32x4 y = *(const ui32x4*)(YT + ytix(row, c0));
          short* hp_ = H + ytix(row, c0);
          ui32x4 hv = *(const ui32x4*)hp_;
          ui32x4 o;
          #pragma unroll
          for (int p=0;p<4;++p){
            f32x2 rg = gp[p] * f32x2{r,r};
            f32x2 cp = __builtin_elementwise_fma(f32x2{-m,-m}, rg, bp[p]);
            f32x2 xp = f32x2{bfhalf(y[p],0), bfhalf(y[p],1)};
            f32x2 ov = gelu_pk(__builtin_elementwise_fma(xp, rg, cp));
            f32x2 hp2 = f32x2{bfhalf(hv[p],0), bfhalf(hv[p],1)};
            f32x2 res = (hp2 + ov) * f32x2{mk,mk};
            o[p] = pk_rne(res[0], res[1]);   // RNE: H feeds proj w/o LN
          }
          *(ui32x4*)hp_ = o;
        }
      }
    }
    __syncthreads();
  }

  // ---- proj GEMM (32x192 @ 192x64): A from Pbf, B = b128 swizzled reads of H rows
  {
    int w = tid >> 6;
    if (w < 4){
      int lane = tid & 63, l16 = lane & 15, q = lane >> 4;
      int mt = w >> 1, ntp = w & 1;
      f32x4 pacc[2];
      { f32x4 z = {0.f,0.f,0.f,0.f}; pacc[0] = z; pacc[1] = z; }
      #pragma unroll
      for (int kk=0;kk<6;++kk){
        s16x8 a = *(const s16x8*)&Pbf[(mt*16 + l16)*CC_ + kk*32 + q*8];
        #pragma unroll
        for (int s=0;s<2;++s){
          int n = (ntp*2+s)*16 + l16;
          s16x8 bvv = *(const s16x8*)(H + ytix(HALO_ + n, kk*32 + q*8));
          pacc[s] = __builtin_amdgcn_mfma_f32_16x16x32_bf16(a, bvv, pacc[s], 0, 0, 0);
        }
      }
      #pragma unroll
      for (int s=0;s<2;++s)
        #pragma unroll
        for (int e=0;e<4;e++){
          int m = mt*16 + q*4 + e;
          if (m < 29){
            int n = (ntp*2+s)*16 + l16;
            HP[n*33 + m] = (pacc[s][e] + proj_b[m]) * MB[16 + HALO_ + n];
          }
        }
    }
  }
  __syncthreads();

  // ---- rational-quadratic spline, one thread per t
  if (tid < 64){
    const int n = tid;
    const int tg = tile*TILE_ + n;
    const float msk = MB[16 + HALO_ + n];
    const float* hp = &HP[n*33];
    const float inv_s = 0.07216878364870323f;  // 1/sqrt(192)
    float uw[10], uh[10], ud9[9];
    #pragma unroll
    for (int k=0;k<10;k++){ uw[k] = hp[k]*inv_s; uh[k] = hp[10+k]*inv_s; }
    #pragma unroll
    for (int k=0;k<9;k++) ud9[k] = hp[20+k];

    float cumw[11], cumh[11];
    {
      float mx = uw[0];
      #pragma unroll
      for (int k=1;k<10;k++) mx = fmaxf(mx, uw[k]);
      float ex[10]; float ss = 0.f;
      #pragma unroll
      for (int k=0;k<10;k++){ ex[k] = __expf(uw[k]-mx); ss += ex[k]; }
      float inv = 1.0f/ss;
      cumw[0] = -5.f; float cw = 0.f;
      #pragma unroll
      for (int k=0;k<10;k++){ float wk = 0.001f + 0.99f*(ex[k]*inv); cw += wk; cumw[k+1] = 10.f*cw - 5.f; }
      cumw[10] = 5.f;
    }
    {
      float mx = uh[0];
      #pragma unroll
      for (int k=1;k<10;k++) mx = fmaxf(mx, uh[k]);
      float ex[10]; float ss = 0.f;
      #pragma unroll
      for (int k=0;k<10;k++){ ex[k] = __expf(uh[k]-mx); ss += ex[k]; }
      float inv = 1.0f/ss;
      cumh[0] = -5.f; float ch = 0.f;
      #pragma unroll
      for (int k=0;k<10;k++){ float hk = 0.001f + 0.99f*(ex[k]*inv); ch += hk; cumh[k+1] = 10.f*ch - 5.f; }
      cumh[10] = 5.f;
    }
    float dv[11];
    dv[0] = 1.0f; dv[10] = 1.0f;
    #pragma unroll
    for (int k=0;k<9;k++){
      float u = ud9[k];
      float sp = (u > 15.f) ? u : log1pf(__expf(u));
      dv[k+1] = 0.001f + sp;
    }

    const float x1 = x[(b*2+1)*TT_ + tg];
    const float xin = fminf(fmaxf(x1, -5.f), 5.f);
    int cnt = 0;
    #pragma unroll
    for (int k=0;k<11;k++){
      float lk = cumw[k] + ((k==10) ? 1e-6f : 0.f);
      cnt += (xin >= lk) ? 1 : 0;
    }
    int bin = cnt - 1;
    bin = (bin < 0) ? 0 : ((bin > 9) ? 9 : bin);

    float icw=0.f, iw=1.f, ich=0.f, ih=1.f, dl=1.f, dr=1.f;
    #pragma unroll
    for (int k=0;k<10;k++){
      if (bin == k){
        icw = cumw[k]; iw = cumw[k+1]-cumw[k];
        ich = cumh[k]; ih = cumh[k+1]-cumh[k];
        dl = dv[k]; dr = dv[k+1];
      }
    }
    float delta = ih/iw;
    float th = (xin - icw)/iw;
    float t1m = th*(1.f-th);
    float num = ih*(delta*th*th + dl*t1m);
    float den = delta + (dl + dr - 2.f*delta)*t1m;
    float yv = ich + num/den;
    float omt = 1.f - th;
    float dnum = delta*delta*(dr*th*th + 2.f*delta*t1m + dl*omt*omt);
    float lad = logf(dnum) - 2.f*logf(den);
    bool inside = (x1 >= -5.f) && (x1 <= 5.f);
    float outv = inside ? yv : x1;
    float ladv = inside ? lad : 0.f;

    out[(b*2)*TT_ + tg]   = x[(b*2)*TT_ + tg] * msk;
    out[(b*2+1)*TT_ + tg] = outv * msk;

    float lsum = ladv * msk;
    #pragma unroll
    for (int off = 32; off > 0; off >>= 1) lsum += __shfl_xor(lsum, off);
    if (tid == 0) part[b*64 + tile] = lsum;
  }
}

// ---- pre-pass: convert pw_w / proj_w to bf16 in workspace
__global__ void convflow_pre(const float* __restrict__ pw_w, const float* __restrict__ proj_w,
                             short* __restrict__ Wbf, short* __restrict__ Pbf){
  int idx = blockIdx.x*256 + threadIdx.x;
  if (idx < 110592) Wbf[idx] = f2bf(pw_w[idx]);
  if (idx < 32*192){
    int m = idx / 192, k = idx - m*192;
    Pbf[idx] = (m < 29) ? f2bf(proj_w[m*192 + k]) : (short)0;
  }
}

// ---- logdet reduction: 64 tiles per batch
__global__ void convflow_logdet(const float* __restrict__ part, float* __restrict__ out){
  int bb = threadIdx.x;
  if (bb < 64){
    float s = 0.f;
    for (int k=0;k<64;k++) s += part[bb*64 + k];
    out[524288 + bb] = s;
  }
}

extern "C" void kernel_launch(void* const* d_in, const int* in_sizes, int n_in,
                              void* d_out, int out_size, void* d_ws, size_t ws_size,
                              hipStream_t stream) {
  const float* x      = (const float*)d_in[0];
  const float* xmask  = (const float*)d_in[1];
  const float* pre_w  = (const float*)d_in[2];
  const float* pre_b  = (const float*)d_in[3];
  const float* sep_w  = (const float*)d_in[4];
  const float* sep_b  = (const float*)d_in[5];
  const float* pw_w   = (const float*)d_in[6];
  const float* pw_b   = (const float*)d_in[7];
  const float* ln1_g  = (const float*)d_in[8];
  const float* ln1_b  = (const float*)d_in[9];
  const float* ln2_g  = (const float*)d_in[10];
  const float* ln2_b  = (const float*)d_in[11];
  const float* proj_w = (const float*)d_in[12];
  const float* proj_b = (const float*)d_in[13];

  short* Wbf = (short*)d_ws;                              // 3*192*192 bf16
  short* Pbf = (short*)((char*)d_ws + 221184);            // 32*192 bf16
  float* part = (float*)((char*)d_ws + 233472);           // 4096 floats
  float* out = (float*)d_out;

  convflow_pre<<<432, 256, 0, stream>>>(pw_w, proj_w, Wbf, Pbf);
  dim3 grid(64, 64);  // (tile, batch)
  convflow_main<<<grid, NT_, 0, stream>>>(x, xmask, pre_w, pre_b, sep_w, sep_b, pw_b,
                                          ln1_g, ln1_b, ln2_g, ln2_b, proj_b,
                                          Wbf, Pbf, out, part);
  convflow_logdet<<<1, 64, 0, stream>>>(part, out);
}

// Round 14
// 561.574 us; speedup vs baseline: 1.2126x; 1.2126x over previous
//
#include <hip/hip_runtime.h>
#include <stdint.h>

#define TT_ 4096
#define CC_ 192
#define TILE_ 64
#define HALO_ 13
#define TW_ 90
#define YTS_ 200    // row stride (shorts) for BOTH H and YT = 100 dwords
#define NT_ 512

typedef float f32x2 __attribute__((ext_vector_type(2)));
typedef float f32x4 __attribute__((ext_vector_type(4)));
typedef short s16x8 __attribute__((ext_vector_type(8)));
typedef uint32_t ui32x2 __attribute__((ext_vector_type(2)));
typedef uint32_t ui32x4 __attribute__((ext_vector_type(4)));

__device__ __forceinline__ float bf2f(short s){
  uint32_t u = ((uint32_t)(uint16_t)s) << 16;
  float f; __builtin_memcpy(&f, &u, 4); return f;
}
// extract bf16 half of a dword as f32: hi=0 -> low short, hi=1 -> high short
__device__ __forceinline__ float bfhalf(uint32_t u, int hi){
  uint32_t v = hi ? (u & 0xFFFF0000u) : (u << 16);
  float f; __builtin_memcpy(&f, &v, 4); return f;
}
__device__ __forceinline__ short f2bf(float f){
  uint32_t u; __builtin_memcpy(&u, &f, 4);
  u += 0x7FFFu + ((u >> 16) & 1u);   // RNE
  return (short)(u >> 16);
}
__device__ __forceinline__ uint32_t fbits(float f){
  uint32_t u; __builtin_memcpy(&u, &f, 4); return u;
}
// pack two f32 -> two bf16 (TRUNCATE) in ONE v_perm_b32. low16 = lo, high16 = hi.
__device__ __forceinline__ uint32_t pk_trunc(float lo, float hi){
  return __builtin_amdgcn_perm(fbits(hi), fbits(lo), 0x07060302u);
}
__device__ __forceinline__ uint32_t rne_u(float f){
  uint32_t u = fbits(f);
  return u + 0x7FFFu + ((u >> 16) & 1u);
}
// pack two f32 -> two bf16 (RNE): 2x3 ops + 1 perm
__device__ __forceinline__ uint32_t pk_rne(float lo, float hi){
  return __builtin_amdgcn_perm(rne_u(hi), rne_u(lo), 0x07060302u);
}
// tanh-form GELU, log2e folded: exp(-p) = exp2(-p*log2e) -> raw v_exp_f32,
// saves 1 VALU op per GELU (r10-proven)
__device__ __forceinline__ float gelu_f(float x){
  float t = x*x;
  float p = x*__builtin_fmaf(t, 0.1029432609f, 2.3022085351f);
  float e = __builtin_amdgcn_exp2f(-p);
  return x * __builtin_amdgcn_rcpf(1.0f + e);
}
// granule swizzle (shared by H and YT): 16B granule g of row r stored at g ^ (r&3).
// Spreads strided row accesses (GEMM B-reads, conv column taps) to the bank floor.
// Bank-quad parity == granule parity: access patterns must mix granule parity
// across the wave (see ln_stats).
__device__ __forceinline__ int ytix(int row, int col){
  return row*YTS_ + ((((col >> 3) ^ (row & 3)) << 3) | (col & 7));
}

// ---- depthwise conv, time-major, FIXED-GRANULE (r5-proven): thread owns granule
// gr for the whole pass; weights/bias loaded ONCE, rows marched stride 21.
// SCALAR math (packed dw spills at the fixed 64-arch-VGPR envelope, r8/r11-13).
template<int D>
__device__ __forceinline__ void dw_pass(const short* __restrict__ Hs, short* __restrict__ YTs,
    const float* __restrict__ sw, const float* __restrict__ sb,
    int jlo, int jhi, int tid){
  if (tid >= 504) return;
  const int gr = tid % 24, r0 = tid / 24;
  const int c0 = gr*8;
  float wv[24], bw[8];
  #pragma unroll
  for (int u=0;u<6;++u) *(f32x4*)&wv[u*4] = *(const f32x4*)&sw[c0*3 + u*4];
  *(f32x4*)&bw[0] = *(const f32x4*)&sb[c0];
  *(f32x4*)&bw[4] = *(const f32x4*)&sb[c0+4];
  for (int j = jlo + r0; j < jhi; j += 21){
    s16x8 t0 = *(const s16x8*)(Hs + ytix(j-D, c0));
    s16x8 t1 = *(const s16x8*)(Hs + ytix(j,   c0));
    s16x8 t2 = *(const s16x8*)(Hs + ytix(j+D, c0));
    float v[8];
    #pragma unroll
    for (int e=0;e<8;++e){
      v[e] = __builtin_fmaf(wv[e*3+0], bf2f(t0[e]),
             __builtin_fmaf(wv[e*3+1], bf2f(t1[e]),
             __builtin_fmaf(wv[e*3+2], bf2f(t2[e]), bw[e])));
    }
    ui32x4 o;
    #pragma unroll
    for (int e=0;e<4;++e) o[e] = pk_trunc(v[2*e], v[2*e+1]);   // trunc: LN follows
    *(ui32x4*)(YTs + ytix(j, c0)) = o;
  }
}

// ---- per-time-row LN stats; 4 threads/row, quad shuffle; packed f32x2 accumulate.
// Column slice: granules {qtr+4u} (col = qtr*8 + u*32) -> wave granule parity
// follows qtr (32/32 even-odd) -> bank floor (r10-proven, -9% conflicts).
__device__ __forceinline__ void ln_stats(const short* __restrict__ YTs, float* __restrict__ SM,
                                         float* __restrict__ SR, int jlo, int jhi, int tid){
  if (tid < 384){
    int row = tid >> 2, qtr = tid & 3;
    if (row >= jlo && row < jhi){
      f32x2 sp = {0.f,0.f}, qp = {0.f,0.f};
      #pragma unroll
      for (int u=0;u<6;++u){
        ui32x4 v = *(const ui32x4*)(YTs + ytix(row, qtr*8 + u*32));
        #pragma unroll
        for (int d=0;d<4;++d){
          f32x2 f = f32x2{bfhalf(v[d],0), bfhalf(v[d],1)};
          sp += f; qp = __builtin_elementwise_fma(f, f, qp);
        }
      }
      float s = sp[0]+sp[1], q = qp[0]+qp[1];
      s += __shfl_xor(s,1); q += __shfl_xor(q,1);
      s += __shfl_xor(s,2); q += __shfl_xor(q,2);
      if (qtr==0){
        float mean = s*(1.f/192.f);
        float var = fmaxf(q*(1.f/192.f) - mean*mean, 0.f);
        SM[row]=mean; SR[row]=rsqrtf(var+1e-5f);
      }
    }
  }
}

__global__ __launch_bounds__(512, 4)
void convflow_main(
    const float* __restrict__ x, const float* __restrict__ xmask,
    const float* __restrict__ pre_w, const float* __restrict__ pre_b,
    const float* __restrict__ sep_w, const float* __restrict__ sep_b,
    const float* __restrict__ pw_b,
    const float* __restrict__ ln1_g, const float* __restrict__ ln1_b,
    const float* __restrict__ ln2_g, const float* __restrict__ ln2_b,
    const float* __restrict__ proj_b,
    const short* __restrict__ Wbf, const short* __restrict__ Pbf,
    float* __restrict__ out, float* __restrict__ part)
{
  __shared__ __align__(16) char smem_raw[78592];
  float* MB = (float*)(smem_raw + 0);        // [160]: mask at idx j+16, zero outside valid t
  float* XB = (float*)(smem_raw + 640);      // [96]
  float* SM = (float*)(smem_raw + 1024);     // [96]
  float* SR = (float*)(smem_raw + 1408);     // [96]
  short* H  = (short*)(smem_raw + 1792);     // [96][200] bf16 time-major, granule-swizzled
  short* YT = (short*)(smem_raw + 40192);    // [96][200] bf16 time-major, granule-swizzled
  float* HP = (float*)(smem_raw + 65792);    // alias YT rows 64..95: [64][33] proj out

  const int tid = threadIdx.x;
  const int b = blockIdx.y, tile = blockIdx.x;
  const int t0 = tile*TILE_ - HALO_;

  // ---- setup mask + x0 window
  for (int idx = tid; idx < 160; idx += NT_){
    int j = idx - 16; int t = t0 + j;
    float m = 0.f;
    if (j >= 0 && j < TW_ && t >= 0 && t < TT_) m = xmask[b*TT_ + t];
    MB[idx] = m;
  }
  if (tid < 96){
    int t = t0 + tid; float v = 0.f;
    if (tid < TW_ && t >= 0 && t < TT_) v = x[(b*2)*TT_ + t];
    XB[tid] = v;
  }
  __syncthreads();

  // ---- h0 = (pre_w*x0 + pre_b)*mask -> H bf16 (RNE: H feeds proj w/o LN)
  // fixed-granule: params loaded once
  if (tid < 504){
    const int gr = tid % 24, r0 = tid / 24;
    const int c = gr*8;
    f32x4 wa = *(const f32x4*)&pre_w[c], wb = *(const f32x4*)&pre_w[c+4];
    f32x4 ba = *(const f32x4*)&pre_b[c], bb = *(const f32x4*)&pre_b[c+4];
    for (int j = r0; j < 96; j += 21){
      float xv = XB[j], mv = MB[16+j];
      float v[8];
      #pragma unroll
      for (int e=0;e<4;++e) v[e]   = (wa[e]*xv + ba[e])*mv;
      #pragma unroll
      for (int e=0;e<4;++e) v[4+e] = (wb[e]*xv + bb[e])*mv;
      ui32x4 o;
      #pragma unroll
      for (int e=0;e<4;++e) o[e] = pk_rne(v[2*e], v[2*e+1]);
      *(ui32x4*)(H + ytix(j, c)) = o;
    }
  }
  __syncthreads();

  // ---- 3 WN layers (7 barriers/layer, r5-proven structure)
  #pragma unroll 1
  for (int li = 0; li < 3; ++li){
    const int jlo = (li==0) ? 1 : ((li==1) ? 4 : 13);
    const int jhi = (li==0) ? 89 : ((li==1) ? 86 : 77);
    const float* sw = sep_w + li*CC_*3;
    const float* sb = sep_b + li*CC_;

    if (li == 0)      dw_pass<1>(H, YT, sw, sb, jlo, jhi, tid);
    else if (li == 1) dw_pass<3>(H, YT, sw, sb, jlo, jhi, tid);
    else              dw_pass<9>(H, YT, sw, sb, jlo, jhi, tid);
    __syncthreads();

    ln_stats(YT, SM, SR, jlo, jhi, tid); __syncthreads();

    // ---- LN1 + gelu in place on YT; VALID ROWS ONLY (r6/r7-proven: invalid YT
    // rows feed only invalid GEMM output rows, never consumed downstream). SCALAR.
    {
      const float* g1 = ln1_g + li*CC_;
      const float* b1 = ln1_b + li*CC_;
      if (tid < 504){
        const int gr = tid % 24, r0 = tid / 24;
        const int c0 = gr*8;
        f32x4 ga = *(const f32x4*)&g1[c0], gb = *(const f32x4*)&g1[c0+4];
        f32x4 ba = *(const f32x4*)&b1[c0], bb = *(const f32x4*)&b1[c0+4];
        for (int row = jlo + r0; row < jhi; row += 21){
          const float m = SM[row], r = SR[row];
          short* p = YT + ytix(row, c0);
          s16x8 v = *(s16x8*)p;
          float ov[8];
          #pragma unroll
          for (int e=0;e<4;e++)
            ov[e] = gelu_f((bf2f(v[e]) - m)*r*ga[e] + ba[e]);
          #pragma unroll
          for (int e=4;e<8;e++)
            ov[e] = gelu_f((bf2f(v[e]) - m)*r*gb[e-4] + bb[e-4]);
          ui32x4 o;
          #pragma unroll
          for (int e=0;e<4;e++) o[e] = pk_trunc(ov[2*e], ov[2*e+1]);
          *(ui32x4*)p = o;
        }
      }
    }
    __syncthreads();

    // ---- pointwise 192x192 GEMM in place on YT: 8 waves = (4 M x 2 N), 3x3 tiles each
    {
      int w = tid >> 6, lane = tid & 63, l16 = lane & 15, q = lane >> 4;
      int Mh = w & 3, Nh = w >> 2;
      f32x4 acc[3][3];
      #pragma unroll
      for (int r=0;r<3;r++)
        #pragma unroll
        for (int s=0;s<3;s++){ f32x4 z = {0.f,0.f,0.f,0.f}; acc[r][s] = z; }
      const short* Wl = Wbf + li*CC_*CC_;
      #pragma unroll
      for (int kk=0;kk<6;++kk){
        s16x8 bv[3], av[3];
        #pragma unroll
        for (int s=0;s<3;++s)
          bv[s] = *(const s16x8*)&YT[ytix((Nh*3+s)*16 + l16, kk*32 + q*8)];
        #pragma unroll
        for (int r=0;r<3;++r)
          av[r] = *(const s16x8*)&Wl[((Mh*3+r)*16 + l16)*CC_ + kk*32 + q*8];
        #pragma unroll
        for (int r=0;r<3;++r)
          #pragma unroll
          for (int s=0;s<3;++s)
            acc[r][s] = __builtin_amdgcn_mfma_f32_16x16x32_bf16(av[r], bv[s], acc[r][s], 0, 0, 0);
      }
      __syncthreads();   // all B reads complete before in-place writes
      #pragma unroll
      for (int r=0;r<3;++r){
        int m0 = (Mh*3+r)*16 + q*4;
        f32x4 bias = *(const f32x4*)&pw_b[li*CC_ + m0];
        #pragma unroll
        for (int s=0;s<3;++s){
          int n = (Nh*3+s)*16 + l16;
          ui32x2 ov;
          ov[0] = pk_trunc(acc[r][s][0]+bias[0], acc[r][s][1]+bias[1]);
          ov[1] = pk_trunc(acc[r][s][2]+bias[2], acc[r][s][3]+bias[3]);
          *(ui32x2*)(YT + ytix(n, m0)) = ov;
        }
      }
      __syncthreads();
    }

    ln_stats(YT, SM, SR, jlo, jhi, tid); __syncthreads();

    // ---- LN2 + gelu + residual into H; fixed-granule, params once. SCALAR.
    {
      const float* g2 = ln2_g + li*CC_;
      const float* b2 = ln2_b + li*CC_;
      if (tid < 504){
        const int gr = tid % 24, r0 = tid / 24;
        const int c0 = gr*8;
        f32x4 ga = *(const f32x4*)&g2[c0], gb = *(const f32x4*)&g2[c0+4];
        f32x4 ba = *(const f32x4*)&b2[c0], bb = *(const f32x4*)&b2[c0+4];
        for (int row = jlo + r0; row < jhi; row += 21){
          const float m = SM[row], r = SR[row], mk = MB[16+row];
          s16x8 y = *(const s16x8*)(YT + ytix(row, c0));
          short* hp_ = H + ytix(row, c0);
          s16x8 hv = *(const s16x8*)hp_;
          float hf[8];
          #pragma unroll
          for (int e=0;e<4;++e){
            float val = (bf2f(y[e]) - m)*r*ga[e] + ba[e];
            hf[e] = (bf2f(hv[e]) + gelu_f(val))*mk;
          }
          #pragma unroll
          for (int e=4;e<8;++e){
            float val = (bf2f(y[e]) - m)*r*gb[e-4] + bb[e-4];
            hf[e] = (bf2f(hv[e]) + gelu_f(val))*mk;
          }
          ui32x4 o;   // RNE: H feeds proj w/o LN
          #pragma unroll
          for (int e=0;e<4;++e) o[e] = pk_rne(hf[2*e], hf[2*e+1]);
          *(ui32x4*)hp_ = o;
        }
      }
    }
    __syncthreads();
  }

  // ---- proj GEMM (32x192 @ 192x64): A from Pbf, B = b128 swizzled reads of H rows
  {
    int w = tid >> 6;
    if (w < 4){
      int lane = tid & 63, l16 = lane & 15, q = lane >> 4;
      int mt = w >> 1, ntp = w & 1;
      f32x4 pacc[2];
      { f32x4 z = {0.f,0.f,0.f,0.f}; pacc[0] = z; pacc[1] = z; }
      #pragma unroll
      for (int kk=0;kk<6;++kk){
        s16x8 a = *(const s16x8*)&Pbf[(mt*16 + l16)*CC_ + kk*32 + q*8];
        #pragma unroll
        for (int s=0;s<2;++s){
          int n = (ntp*2+s)*16 + l16;
          s16x8 bvv = *(const s16x8*)(H + ytix(HALO_ + n, kk*32 + q*8));
          pacc[s] = __builtin_amdgcn_mfma_f32_16x16x32_bf16(a, bvv, pacc[s], 0, 0, 0);
        }
      }
      #pragma unroll
      for (int s=0;s<2;++s)
        #pragma unroll
        for (int e=0;e<4;e++){
          int m = mt*16 + q*4 + e;
          if (m < 29){
            int n = (ntp*2+s)*16 + l16;
            HP[n*33 + m] = (pacc[s][e] + proj_b[m]) * MB[16 + HALO_ + n];
          }
        }
    }
  }
  __syncthreads();

  // ---- rational-quadratic spline, one thread per t
  if (tid < 64){
    const int n = tid;
    const int tg = tile*TILE_ + n;
    const float msk = MB[16 + HALO_ + n];
    const float* hp = &HP[n*33];
    const float inv_s = 0.07216878364870323f;  // 1/sqrt(192)
    float uw[10], uh[10], ud9[9];
    #pragma unroll
    for (int k=0;k<10;k++){ uw[k] = hp[k]*inv_s; uh[k] = hp[10+k]*inv_s; }
    #pragma unroll
    for (int k=0;k<9;k++) ud9[k] = hp[20+k];

    float cumw[11], cumh[11];
    {
      float mx = uw[0];
      #pragma unroll
      for (int k=1;k<10;k++) mx = fmaxf(mx, uw[k]);
      float ex[10]; float ss = 0.f;
      #pragma unroll
      for (int k=0;k<10;k++){ ex[k] = __expf(uw[k]-mx); ss += ex[k]; }
      float inv = 1.0f/ss;
      cumw[0] = -5.f; float cw = 0.f;
      #pragma unroll
      for (int k=0;k<10;k++){ float wk = 0.001f + 0.99f*(ex[k]*inv); cw += wk; cumw[k+1] = 10.f*cw - 5.f; }
      cumw[10] = 5.f;
    }
    {
      float mx = uh[0];
      #pragma unroll
      for (int k=1;k<10;k++) mx = fmaxf(mx, uh[k]);
      float ex[10]; float ss = 0.f;
      #pragma unroll
      for (int k=0;k<10;k++){ ex[k] = __expf(uh[k]-mx); ss += ex[k]; }
      float inv = 1.0f/ss;
      cumh[0] = -5.f; float ch = 0.f;
      #pragma unroll
      for (int k=0;k<10;k++){ float hk = 0.001f + 0.99f*(ex[k]*inv); ch += hk; cumh[k+1] = 10.f*ch - 5.f; }
      cumh[10] = 5.f;
    }
    float dv[11];
    dv[0] = 1.0f; dv[10] = 1.0f;
    #pragma unroll
    for (int k=0;k<9;k++){
      float u = ud9[k];
      float sp = (u > 15.f) ? u : log1pf(__expf(u));
      dv[k+1] = 0.001f + sp;
    }

    const float x1 = x[(b*2+1)*TT_ + tg];
    const float xin = fminf(fmaxf(x1, -5.f), 5.f);
    int cnt = 0;
    #pragma unroll
    for (int k=0;k<11;k++){
      float lk = cumw[k] + ((k==10) ? 1e-6f : 0.f);
      cnt += (xin >= lk) ? 1 : 0;
    }
    int bin = cnt - 1;
    bin = (bin < 0) ? 0 : ((bin > 9) ? 9 : bin);

    float icw=0.f, iw=1.f, ich=0.f, ih=1.f, dl=1.f, dr=1.f;
    #pragma unroll
    for (int k=0;k<10;k++){
      if (bin == k){
        icw = cumw[k]; iw = cumw[k+1]-cumw[k];
        ich = cumh[k]; ih = cumh[k+1]-cumh[k];
        dl = dv[k]; dr = dv[k+1];
      }
    }
    float delta = ih/iw;
    float th = (xin - icw)/iw;
    float t1m = th*(1.f-th);
    float num = ih*(delta*th*th + dl*t1m);
    float den = delta + (dl + dr - 2.f*delta)*t1m;
    float yv = ich + num/den;
    float omt = 1.f - th;
    float dnum = delta*delta*(dr*th*th + 2.f*delta*t1m + dl*omt*omt);
    float lad = logf(dnum) - 2.f*logf(den);
    bool inside = (x1 >= -5.f) && (x1 <= 5.f);
    float outv = inside ? yv : x1;
    float ladv = inside ? lad : 0.f;

    out[(b*2)*TT_ + tg]   = x[(b*2)*TT_ + tg] * msk;
    out[(b*2+1)*TT_ + tg] = outv * msk;

    float lsum = ladv * msk;
    #pragma unroll
    for (int off = 32; off > 0; off >>= 1) lsum += __shfl_xor(lsum, off);
    if (tid == 0) part[b*64 + tile] = lsum;
  }
}

// ---- pre-pass: convert pw_w / proj_w to bf16 in workspace
__global__ void convflow_pre(const float* __restrict__ pw_w, const float* __restrict__ proj_w,
                             short* __restrict__ Wbf, short* __restrict__ Pbf){
  int idx = blockIdx.x*256 + threadIdx.x;
  if (idx < 110592) Wbf[idx] = f2bf(pw_w[idx]);
  if (idx < 32*192){
    int m = idx / 192, k = idx - m*192;
    Pbf[idx] = (m < 29) ? f2bf(proj_w[m*192 + k]) : (short)0;
  }
}

// ---- logdet reduction: 64 tiles per batch
__global__ void convflow_logdet(const float* __restrict__ part, float* __restrict__ out){
  int bb = threadIdx.x;
  if (bb < 64){
    float s = 0.f;
    for (int k=0;k<64;k++) s += part[bb*64 + k];
    out[524288 + bb] = s;
  }
}

extern "C" void kernel_launch(void* const* d_in, const int* in_sizes, int n_in,
                              void* d_out, int out_size, void* d_ws, size_t ws_size,
                              hipStream_t stream) {
  const float* x      = (const float*)d_in[0];
  const float* xmask  = (const float*)d_in[1];
  const float* pre_w  = (const float*)d_in[2];
  const float* pre_b  = (const float*)d_in[3];
  const float* sep_w  = (const float*)d_in[4];
  const float* sep_b  = (const float*)d_in[5];
  const float* pw_w   = (const float*)d_in[6];
  const float* pw_b   = (const float*)d_in[7];
  const float* ln1_g  = (const float*)d_in[8];
  const float* ln1_b  = (const float*)d_in[9];
  const float* ln2_g  = (const float*)d_in[10];
  const float* ln2_b  = (const float*)d_in[11];
  const float* proj_w = (const float*)d_in[12];
  const float* proj_b = (const float*)d_in[13];

  short* Wbf = (short*)d_ws;                              // 3*192*192 bf16
  short* Pbf = (short*)((char*)d_ws + 221184);            // 32*192 bf16
  float* part = (float*)((char*)d_ws + 233472);           // 4096 floats
  float* out = (float*)d_out;

  convflow_pre<<<432, 256, 0, stream>>>(pw_w, proj_w, Wbf, Pbf);
  dim3 grid(64, 64);  // (tile, batch)
  convflow_main<<<grid, NT_, 0, stream>>>(x, xmask, pre_w, pre_b, sep_w, sep_b, pw_b,
                                          ln1_g, ln1_b, ln2_g, ln2_b, proj_b,
                                          Wbf, Pbf, out, part);
  convflow_logdet<<<1, 64, 0, stream>>>(part, out);
}